// Round 1
// baseline (733.197 us; speedup 1.0000x reference)
//
#include <hip/hip_runtime.h>
#include <math.h>

#define B 64
#define S 2048
#define D 1024
#define H 300
#define NOUT 2
#define NCHUNK 32
#define CHUNK_S (S / NCHUNK) /* 64 = one wave */

typedef float fx4 __attribute__((ext_vector_type(4)));

static __device__ __forceinline__ int imin(int a, int b) { return a < b ? a : b; }

// ---------------------------------------------------------------------------
// Kernel 1: end_ind[b] = first s with input_ids[b,s]==1, fallback B (= shape[0])
// ---------------------------------------------------------------------------
__global__ __launch_bounds__(256) void end_kernel(const int* __restrict__ ids,
                                                  int* __restrict__ end_ind) {
    int b = blockIdx.x;
    int t = threadIdx.x;
    const int* row = ids + (size_t)b * S;
    int m = S;
    for (int s = t; s < S; s += 256) {
        if (row[s] == 1 && s < m) m = s;
    }
    __shared__ int red[256];
    red[t] = m;
    __syncthreads();
    for (int st = 128; st > 0; st >>= 1) {
        if (t < st) red[t] = imin(red[t], red[t + st]);
        __syncthreads();
    }
    if (t == 0) end_ind[b] = (red[0] < S) ? red[0] : B;
}

// ---------------------------------------------------------------------------
// Kernel 2: deterministic partial sums with dropped-row skipping.
// Block (chunk, b); CHUNK_S = 64 rows = one wave's worth of drop values.
// Wave 0 ballot-compacts the active-row list (order-preserving, deterministic,
// no atomics), then all 256 threads stream only the ~80% surviving rows with
// regular cached fx4 loads, 8 rows in flight per thread.
// ---------------------------------------------------------------------------
__global__ __launch_bounds__(256) void sum_partial_kernel(
        const float* __restrict__ inputs,
        const float* __restrict__ drop,
        const int* __restrict__ end_ind,
        float* __restrict__ partial /* [B][NCHUNK][D] */) {
    int chunk = blockIdx.x;
    int b = blockIdx.y;
    int t = threadIdx.x;

    __shared__ int   rows_l[CHUNK_S];
    __shared__ float w_l[CHUNK_S];
    __shared__ int   cnt_l;

    int e = end_ind[b];
    int s0 = chunk * CHUNK_S;
    int n = imin(s0 + CHUNK_S, e) - s0;   // rows valid in this chunk (may be <=0)

    if (t < 64) {
        float w = 0.f;
        if (t < n) w = drop[(size_t)b * S + s0 + t];
        unsigned long long mask = __ballot(w != 0.f);
        int pos = __popcll(mask & ((1ull << t) - 1ull));
        if (w != 0.f) { rows_l[pos] = t; w_l[pos] = w; }
        if (t == 0) cnt_l = __popcll(mask);
    }
    __syncthreads();

    int m = cnt_l;
    fx4 a0 = (fx4)(0.f);
    fx4 a1 = a0, a2 = a0, a3 = a0, a4 = a0, a5 = a0, a6 = a0, a7 = a0;

    // thread t owns bytes [16t, 16t+16) of each 4KB row
    const char* base = (const char*)inputs + (((size_t)b * S + s0) * D + 4 * (size_t)t) * sizeof(float);

    int i = 0;
    for (; i + 8 <= m; i += 8) {
        fx4 v0 = *(const fx4*)(base + ((size_t)rows_l[i + 0] << 12));
        fx4 v1 = *(const fx4*)(base + ((size_t)rows_l[i + 1] << 12));
        fx4 v2 = *(const fx4*)(base + ((size_t)rows_l[i + 2] << 12));
        fx4 v3 = *(const fx4*)(base + ((size_t)rows_l[i + 3] << 12));
        fx4 v4 = *(const fx4*)(base + ((size_t)rows_l[i + 4] << 12));
        fx4 v5 = *(const fx4*)(base + ((size_t)rows_l[i + 5] << 12));
        fx4 v6 = *(const fx4*)(base + ((size_t)rows_l[i + 6] << 12));
        fx4 v7 = *(const fx4*)(base + ((size_t)rows_l[i + 7] << 12));
        a0 += v0 * w_l[i + 0];
        a1 += v1 * w_l[i + 1];
        a2 += v2 * w_l[i + 2];
        a3 += v3 * w_l[i + 3];
        a4 += v4 * w_l[i + 4];
        a5 += v5 * w_l[i + 5];
        a6 += v6 * w_l[i + 6];
        a7 += v7 * w_l[i + 7];
    }
    for (; i < m; ++i) {
        fx4 v = *(const fx4*)(base + ((size_t)rows_l[i] << 12));
        a0 += v * w_l[i];
    }
    a0 = ((a0 + a1) + (a2 + a3)) + ((a4 + a5) + (a6 + a7));

    // Every block writes (zeros for fully-skipped chunks) -> no memset needed.
    fx4* op = (fx4*)(partial + ((size_t)b * NCHUNK + chunk) * D) + t;
    *op = a0;
}

// ---------------------------------------------------------------------------
// Kernel 3: per-batch-row MLP, coalesced W1 access.
// Reduce NCHUNK partials -> x (LDS -> 4 regs/lane), then one wave per hidden
// unit h: lanes split the 4KB W1 row (1KB contiguous per instruction),
// shfl_xor wave reduction. Then out = hidden @ W2^T + b2.
// ---------------------------------------------------------------------------
__global__ __launch_bounds__(256) void mlp_kernel(
        const float* __restrict__ partial,
        const int* __restrict__ end_ind,
        const float* __restrict__ W1, const float* __restrict__ b1,
        const float* __restrict__ W2, const float* __restrict__ b2,
        float* __restrict__ out) {
    int b = blockIdx.x;
    int t = threadIdx.x;
    int wave = t >> 6;
    int lane = t & 63;

    __shared__ fx4 x4[D / 4];        // 4 KB: euph row
    __shared__ float hidden[H];      // 1.2 KB
    __shared__ float red[256];

    float inv_e = 1.0f / (float)end_ind[b];
    {
        fx4 a = (fx4)(0.f);
        const fx4* p = (const fx4*)(partial + (size_t)b * NCHUNK * D) + t;
        for (int c = 0; c < NCHUNK; ++c, p += D / 4) {
            a += p[0];
        }
        x4[t] = a * inv_e;
    }
    __syncthreads();

    // each lane caches its 4 fx4 slices of x once (reused for all h)
    fx4 xr0 = x4[lane];
    fx4 xr1 = x4[lane + 64];
    fx4 xr2 = x4[lane + 128];
    fx4 xr3 = x4[lane + 192];

    for (int h = wave; h < H; h += 4) {
        const fx4* w = (const fx4*)(W1 + (size_t)h * D);
        fx4 acc = xr0 * w[lane]
                + xr1 * w[lane + 64]
                + xr2 * w[lane + 128]
                + xr3 * w[lane + 192];
        float d = acc.x + acc.y + acc.z + acc.w;
        #pragma unroll
        for (int mm = 32; mm > 0; mm >>= 1) d += __shfl_xor(d, mm, 64);
        if (lane == 0) hidden[h] = tanhf(d + b1[h]);
    }
    __syncthreads();

    for (int o = 0; o < NOUT; ++o) {
        float p = 0.f;
        for (int h = t; h < H; h += 256) p += hidden[h] * W2[(size_t)o * H + h];
        red[t] = p;
        __syncthreads();
        for (int st = 128; st > 0; st >>= 1) {
            if (t < st) red[t] += red[t + st];
            __syncthreads();
        }
        if (t == 0) out[b * NOUT + o] = red[0] + b2[o];
        __syncthreads();
    }
}

// ---------------------------------------------------------------------------
extern "C" void kernel_launch(void* const* d_in, const int* in_sizes, int n_in,
                              void* d_out, int out_size, void* d_ws, size_t ws_size,
                              hipStream_t stream) {
    const float* inputs = (const float*)d_in[0];
    const int*   ids    = (const int*)d_in[1];
    const float* drop   = (const float*)d_in[2];
    const float* W1     = (const float*)d_in[3];
    const float* b1v    = (const float*)d_in[4];
    const float* W2     = (const float*)d_in[5];
    const float* b2v    = (const float*)d_in[6];
    float* out = (float*)d_out;

    // ws layout: [0,256): end_ind (64 ints, padded); [256, ...): partials (8 MiB)
    int*   end_ind = (int*)d_ws;
    float* partial = (float*)((char*)d_ws + 256);

    end_kernel<<<B, 256, 0, stream>>>(ids, end_ind);
    sum_partial_kernel<<<dim3(NCHUNK, B), 256, 0, stream>>>(inputs, drop, end_ind, partial);
    mlp_kernel<<<B, 256, 0, stream>>>(partial, end_ind, W1, b1v, W2, b2v, out);
}

// Round 2
// 667.568 us; speedup vs baseline: 1.0983x; 1.0983x over previous
//
#include <hip/hip_runtime.h>
#include <math.h>

#define B 64
#define S 2048
#define D 1024
#define H 300
#define NOUT 2
#define NCHUNK 16
#define CHUNK_S (S / NCHUNK) /* 128 */

typedef float fx4 __attribute__((ext_vector_type(4)));

static __device__ __forceinline__ int imin(int a, int b) { return a < b ? a : b; }

// ---------------------------------------------------------------------------
// Kernel 1 (fused): per-block end_ind recompute + deterministic partial sums
// with dropped-row skipping.
// Block (chunk, b). Each block independently scans its row's ids (8 KB,
// L2/L3-resident after first touch) -> e. chunk==0 block publishes end_ind[b]
// for the MLP kernel. Then 2-wave ballot compaction of the CHUNK_S=128 drop
// weights (order-preserving, deterministic, no atomics), and all 256 threads
// stream only surviving rows with nontemporal fx4 loads, 8 rows in flight.
// ---------------------------------------------------------------------------
__global__ __launch_bounds__(256) void sum_partial_kernel(
        const float* __restrict__ inputs,
        const int* __restrict__ ids,
        const float* __restrict__ drop,
        int* __restrict__ end_ind,
        float* __restrict__ partial /* [B][NCHUNK][D] */) {
    int chunk = blockIdx.x;
    int b = blockIdx.y;
    int t = threadIdx.x;
    int lane = t & 63;
    int widx = t >> 6;

    // ---- end_ind: min position of id==1 in this row (fallback B) ----
    const int* idrow = ids + (size_t)b * S;
    int m = S;
    for (int s = t; s < S; s += 256) {
        if (idrow[s] == 1 && s < m) m = s;
    }
    #pragma unroll
    for (int off = 32; off > 0; off >>= 1) m = imin(m, __shfl_xor(m, off, 64));
    __shared__ int wmin[4];
    if (lane == 0) wmin[widx] = m;
    __syncthreads();
    int e_full = imin(imin(wmin[0], wmin[1]), imin(wmin[2], wmin[3]));
    int e = (e_full < S) ? e_full : B;  // reference fallback: shape[0] == B
    if (t == 0 && chunk == 0) end_ind[b] = e;

    // ---- 2-wave ballot compaction of this chunk's drop weights ----
    int s0 = chunk * CHUNK_S;
    int n = imin(s0 + CHUNK_S, e) - s0;  // valid rows in chunk (may be <= 0)

    __shared__ int   rows_l[CHUNK_S];
    __shared__ float w_l[CHUNK_S];
    __shared__ int   wcnt[2];

    float w = 0.f;
    int pos = 0;
    if (t < CHUNK_S) {
        w = (t < n) ? drop[(size_t)b * S + s0 + t] : 0.f;
        unsigned long long mask = __ballot(w != 0.f);
        pos = __popcll(mask & ((1ull << lane) - 1ull));
        if (lane == 0) wcnt[widx] = __popcll(mask);
    }
    __syncthreads();
    int base0 = (widx == 1) ? wcnt[0] : 0;
    if (t < CHUNK_S && w != 0.f) {
        rows_l[base0 + pos] = t;
        w_l[base0 + pos] = w;
    }
    int mtot = wcnt[0] + wcnt[1];
    __syncthreads();

    // ---- stream surviving rows: nontemporal, 8-deep ILP ----
    fx4 a0 = (fx4)(0.f);
    fx4 a1 = a0, a2 = a0, a3 = a0, a4 = a0, a5 = a0, a6 = a0, a7 = a0;

    // thread t owns bytes [16t, 16t+16) of each 4KB row
    const char* base = (const char*)inputs
                     + (((size_t)b * S + s0) * D + 4 * (size_t)t) * sizeof(float);

    int i = 0;
    for (; i + 8 <= mtot; i += 8) {
        fx4 v0 = __builtin_nontemporal_load((const fx4*)(base + ((size_t)rows_l[i + 0] << 12)));
        fx4 v1 = __builtin_nontemporal_load((const fx4*)(base + ((size_t)rows_l[i + 1] << 12)));
        fx4 v2 = __builtin_nontemporal_load((const fx4*)(base + ((size_t)rows_l[i + 2] << 12)));
        fx4 v3 = __builtin_nontemporal_load((const fx4*)(base + ((size_t)rows_l[i + 3] << 12)));
        fx4 v4 = __builtin_nontemporal_load((const fx4*)(base + ((size_t)rows_l[i + 4] << 12)));
        fx4 v5 = __builtin_nontemporal_load((const fx4*)(base + ((size_t)rows_l[i + 5] << 12)));
        fx4 v6 = __builtin_nontemporal_load((const fx4*)(base + ((size_t)rows_l[i + 6] << 12)));
        fx4 v7 = __builtin_nontemporal_load((const fx4*)(base + ((size_t)rows_l[i + 7] << 12)));
        a0 += v0 * w_l[i + 0];
        a1 += v1 * w_l[i + 1];
        a2 += v2 * w_l[i + 2];
        a3 += v3 * w_l[i + 3];
        a4 += v4 * w_l[i + 4];
        a5 += v5 * w_l[i + 5];
        a6 += v6 * w_l[i + 6];
        a7 += v7 * w_l[i + 7];
    }
    for (; i < mtot; ++i) {
        fx4 v = __builtin_nontemporal_load((const fx4*)(base + ((size_t)rows_l[i] << 12)));
        a0 += v * w_l[i];
    }
    a0 = ((a0 + a1) + (a2 + a3)) + ((a4 + a5) + (a6 + a7));

    // Every block writes (zeros for fully-skipped chunks) -> no memset needed.
    fx4* op = (fx4*)(partial + ((size_t)b * NCHUNK + chunk) * D) + t;
    *op = a0;
}

// ---------------------------------------------------------------------------
// Kernel 2: per-batch-row MLP, coalesced W1 access, 8 waves.
// Reduce NCHUNK partials -> x (LDS -> 4 regs/lane), then one wave per hidden
// unit h (h += 8): lanes split the 4KB W1 row (1KB contiguous per
// instruction), shfl_xor wave reduction. Then out = hidden @ W2^T + b2.
// ---------------------------------------------------------------------------
__global__ __launch_bounds__(512) void mlp_kernel(
        const float* __restrict__ partial,
        const int* __restrict__ end_ind,
        const float* __restrict__ W1, const float* __restrict__ b1,
        const float* __restrict__ W2, const float* __restrict__ b2,
        float* __restrict__ out) {
    int b = blockIdx.x;
    int t = threadIdx.x;
    int wave = t >> 6;
    int lane = t & 63;

    __shared__ fx4 x4[D / 4];        // 4 KB: euph row
    __shared__ float hidden[H];      // 1.2 KB
    __shared__ float red[512];

    float inv_e = 1.0f / (float)end_ind[b];
    if (t < D / 4) {
        fx4 a = (fx4)(0.f);
        const fx4* p = (const fx4*)(partial + (size_t)b * NCHUNK * D) + t;
        for (int c = 0; c < NCHUNK; ++c, p += D / 4) {
            a += p[0];
        }
        x4[t] = a * inv_e;
    }
    __syncthreads();

    // each lane caches its 4 fx4 slices of x once (reused for all h)
    fx4 xr0 = x4[lane];
    fx4 xr1 = x4[lane + 64];
    fx4 xr2 = x4[lane + 128];
    fx4 xr3 = x4[lane + 192];

    for (int h = wave; h < H; h += 8) {
        const fx4* w = (const fx4*)(W1 + (size_t)h * D);
        fx4 acc = xr0 * w[lane]
                + xr1 * w[lane + 64]
                + xr2 * w[lane + 128]
                + xr3 * w[lane + 192];
        float d = acc.x + acc.y + acc.z + acc.w;
        #pragma unroll
        for (int mm = 32; mm > 0; mm >>= 1) d += __shfl_xor(d, mm, 64);
        if (lane == 0) hidden[h] = tanhf(d + b1[h]);
    }
    __syncthreads();

    for (int o = 0; o < NOUT; ++o) {
        float p = 0.f;
        for (int h = t; h < H; h += 512) p += hidden[h] * W2[(size_t)o * H + h];
        red[t] = p;
        __syncthreads();
        for (int st = 256; st > 0; st >>= 1) {
            if (t < st) red[t] += red[t + st];
            __syncthreads();
        }
        if (t == 0) out[b * NOUT + o] = red[0] + b2[o];
        __syncthreads();
    }
}

// ---------------------------------------------------------------------------
extern "C" void kernel_launch(void* const* d_in, const int* in_sizes, int n_in,
                              void* d_out, int out_size, void* d_ws, size_t ws_size,
                              hipStream_t stream) {
    const float* inputs = (const float*)d_in[0];
    const int*   ids    = (const int*)d_in[1];
    const float* drop   = (const float*)d_in[2];
    const float* W1     = (const float*)d_in[3];
    const float* b1v    = (const float*)d_in[4];
    const float* W2     = (const float*)d_in[5];
    const float* b2v    = (const float*)d_in[6];
    float* out = (float*)d_out;

    // ws layout: [0,256): end_ind (64 ints, padded); [256, ...): partials (4 MiB)
    int*   end_ind = (int*)d_ws;
    float* partial = (float*)((char*)d_ws + 256);

    sum_partial_kernel<<<dim3(NCHUNK, B), 256, 0, stream>>>(inputs, ids, drop, end_ind, partial);
    mlp_kernel<<<B, 512, 0, stream>>>(partial, end_ind, W1, b1v, W2, b2v, out);
}